// Round 3
// baseline (344.076 us; speedup 1.0000x reference)
//
#include <hip/hip_runtime.h>

// Local variance over a 5x5 sliding window, reflect padding.
// SEPARABLE, VERTICAL-FIRST formulation:
//   pass 1 (registers): vertical 5-row running sums of x and x^2 per thread
//     for its own 4 columns — needs NO horizontal halo, so each thread loads
//     exactly ONE float4 per input row. Block = 256 threads spanning the full
//     W = 1024 -> every row read is one contiguous 4 KB burst (no redundant
//     overlapped halo loads; previous kernel loaded every input byte ~3x).
//   pass 2 (LDS): the per-column vertical sums (sv, sq) are staged in a
//     double-buffered LDS row (2 x 4 KB x 2 arrays); horizontal 5-window is
//     computed from the staged row with the same clamped-read + select edge
//     logic as the register kernel. One barrier per output row (double
//     buffering makes write(i+1) safe against read(i-1)).
//
// Latency: the global load for row i+1 is issued BEFORE row i's barrier, so
// its ~500-900 cyc latency hides under write+barrier+read+compute.
//
// Geometry: RH=32 output rows/block, 36 input rows (1.125x vertical halo).
// Grid (H/32, B*C) = (32, 48) = 1536 blocks = exactly 6 per CU (divides the
// 8 XCDs evenly). LDS 16 KB/block.
//
// Reflect (jnp "reflect"): rows via wave-uniform index math. Columns: window
// c0-2..c0+5 read as two aligned float4 (c0-4, c0+4) + own sums; edges:
//   left  (c0==0):  col -2 -> col 2 == clamped u0.z (auto); col -1 -> col 1 = sv1
//   right (c0==W-4): col W -> col W-2 = sv2; col W+1 -> col W-3 == clamped u2.y (auto)

constexpr int NT = 256;
constexpr int RH = 32;

__global__ __launch_bounds__(NT, 4)
void lvar5x5_sep_kernel(const float* __restrict__ in, float* __restrict__ out,
                        int H, int W) {
    const int tx = threadIdx.x;          // 0..255, covers full row
    const int c0 = tx * 4;               // this thread's 4 columns
    const int r0 = blockIdx.x * RH;      // first output row
    const size_t plane = (size_t)H * W;
    const float* __restrict__ img = in + (size_t)blockIdx.y * plane;
    float* __restrict__ o = out + (size_t)blockIdx.y * plane;

    __shared__ float lsv[2][1024];       // staged vertical sums of x
    __shared__ float lsq[2][1024];       // staged vertical sums of x^2

    const bool cL = (c0 == 0);
    const bool cR = (c0 == W - 4);
    const int a0 = cL ? 0 : c0 - 4;      // clamped left window read (floats)
    const int a2 = cR ? c0 : c0 + 4;     // clamped right window read

    float ring[5][4];                    // raw x ring (x^2 recomputed on retire)
    float sv0 = 0.f, sv1 = 0.f, sv2 = 0.f, sv3 = 0.f;
    float sq0 = 0.f, sq1 = 0.f, sq2 = 0.f, sq3 = 0.f;
    const float inv = 1.0f / 25.0f;

    auto row_ptr = [&](int i) -> const float4* {
        int gy = r0 - 2 + i;
        gy = (gy < 0) ? -gy : ((gy >= H) ? (2 * H - 2 - gy) : gy);
        return reinterpret_cast<const float4*>(img + (size_t)gy * W + c0);
    };

    float4 vc = *row_ptr(0);             // prefetched current row

#pragma unroll
    for (int i = 0; i < RH + 4; ++i) {
        // issue next row's load BEFORE any barrier of this iteration
        float4 vn;
        if (i < RH + 3) vn = *row_ptr(i + 1);

        const int s = i % 5;             // compile-time after unroll
        if (i >= 5) {
            const float o0 = ring[s][0], o1 = ring[s][1],
                        o2 = ring[s][2], o3 = ring[s][3];
            sv0 -= o0; sv1 -= o1; sv2 -= o2; sv3 -= o3;
            sq0 = fmaf(-o0, o0, sq0); sq1 = fmaf(-o1, o1, sq1);
            sq2 = fmaf(-o2, o2, sq2); sq3 = fmaf(-o3, o3, sq3);
        }
        ring[s][0] = vc.x; ring[s][1] = vc.y; ring[s][2] = vc.z; ring[s][3] = vc.w;
        sv0 += vc.x; sv1 += vc.y; sv2 += vc.z; sv3 += vc.w;
        sq0 = fmaf(vc.x, vc.x, sq0); sq1 = fmaf(vc.y, vc.y, sq1);
        sq2 = fmaf(vc.z, vc.z, sq2); sq3 = fmaf(vc.w, vc.w, sq3);

        if (i >= 4) {
            const int sl = i & 1;
            *reinterpret_cast<float4*>(&lsv[sl][c0]) =
                make_float4(sv0, sv1, sv2, sv3);
            *reinterpret_cast<float4*>(&lsq[sl][c0]) =
                make_float4(sq0, sq1, sq2, sq3);
            __syncthreads();

            const float4 u0 = *reinterpret_cast<const float4*>(&lsv[sl][a0]);
            const float4 u2 = *reinterpret_cast<const float4*>(&lsv[sl][a2]);
            const float4 w0 = *reinterpret_cast<const float4*>(&lsq[sl][a0]);
            const float4 w2 = *reinterpret_cast<const float4*>(&lsq[sl][a2]);

            // window cols c0-2 .. c0+5 of the vertical sums
            const float t2 = u0.z;                   // c0-2 (auto at left edge)
            float       t3 = cL ? sv1 : u0.w;        // c0-1 (reflect -1 -> 1)
            float       t8 = cR ? sv2 : u2.x;        // c0+4 (reflect W -> W-2)
            const float t9 = u2.y;                   // c0+5 (auto at right edge)

            const float g2 = w0.z;
            float       g3 = cL ? sq1 : w0.w;
            float       g8 = cR ? sq2 : w2.x;
            const float g9 = w2.y;

            const float h0 = t2 + t3 + sv0 + sv1 + sv2;
            const float h1 = h0 - t2 + sv3;
            const float h2 = h1 - t3 + t8;
            const float h3 = h2 - sv0 + t9;

            const float q0 = g2 + g3 + sq0 + sq1 + sq2;
            const float q1 = q0 - g2 + sq3;
            const float q2 = q1 - g3 + g8;
            const float q3 = q2 - sq0 + g9;

            float4 res;
            float m;
            m = h0 * inv; res.x = fmaf(-m, m, q0 * inv);
            m = h1 * inv; res.y = fmaf(-m, m, q1 * inv);
            m = h2 * inv; res.z = fmaf(-m, m, q2 * inv);
            m = h3 * inv; res.w = fmaf(-m, m, q3 * inv);
            *reinterpret_cast<float4*>(o + (size_t)(r0 + i - 4) * W + c0) = res;
        }
        vc = vn;
    }
}

extern "C" void kernel_launch(void* const* d_in, const int* in_sizes, int n_in,
                              void* d_out, int out_size, void* d_ws, size_t ws_size,
                              hipStream_t stream) {
    const float* image = (const float*)d_in[0];
    float* out = (float*)d_out;

    const int H = 1024, W = 1024;
    const int BC = out_size / (H * W);   // 48

    dim3 grid(H / RH, BC);               // (32, 48) = 1536 blocks
    dim3 block(NT);
    lvar5x5_sep_kernel<<<grid, block, 0, stream>>>(image, out, H, W);
}